// Round 1
// baseline (61.619 us; speedup 1.0000x reference)
//
#include <hip/hip_runtime.h>

// Problem constants (match reference)
#define BQ 32
#define TT 20000
#define NN 200
#define S3 600   // 3*N

// One thread per (b, t). Gathers three 3x3 blocks of H, computes the four
// distinct products T2[u][v] = Mij * S^u * Mjk * S^v * Mki (S = diag(1,1,-1)),
// derives all 8 Frobenius errors from them.
__global__ __launch_bounds__(256) void jcfg_err_kernel(
    const float* __restrict__ H,
    const int*   __restrict__ trip,
    float*       __restrict__ out)
{
    int idx = blockIdx.x * blockDim.x + threadIdx.x;
    if (idx >= BQ * TT) return;
    int b = idx / TT;
    int t = idx - b * TT;

    int i = trip[3 * t + 0];
    int j = trip[3 * t + 1];
    int k = trip[3 * t + 2];

    const float* __restrict__ Hb = H + (size_t)b * (S3 * S3);

    float Mij[3][3], Mjk[3][3], Mki[3][3];
    {
        const int ri = 3 * i, rj = 3 * j, rk = 3 * k;
#pragma unroll
        for (int p = 0; p < 3; ++p) {
            const float* rowIJ = Hb + (size_t)(ri + p) * S3 + rj;
            const float* rowJK = Hb + (size_t)(rj + p) * S3 + rk;
            const float* rowKI = Hb + (size_t)(rk + p) * S3 + ri;
#pragma unroll
            for (int q = 0; q < 3; ++q) {
                Mij[p][q] = rowIJ[q];
                Mjk[p][q] = rowJK[q];
                Mki[p][q] = rowKI[q];
            }
        }
    }

    // N1[u] = Mij * S^u * Mjk.  Split the q=2 contribution so u=0/1 share work.
    float N1[2][3][3];
#pragma unroll
    for (int p = 0; p < 3; ++p) {
#pragma unroll
        for (int r = 0; r < 3; ++r) {
            float c = Mij[p][0] * Mjk[0][r] + Mij[p][1] * Mjk[1][r];
            float d = Mij[p][2] * Mjk[2][r];
            N1[0][p][r] = c + d;
            N1[1][p][r] = c - d;
        }
    }

    // T2[u][v] = N1[u] * S^v * Mki.  Same split on r=2.
    float err[2][2];
#pragma unroll
    for (int u = 0; u < 2; ++u) {
        float T2p[3][3], T2m[3][3];  // v=0 (plus), v=1 (minus)
#pragma unroll
        for (int p = 0; p < 3; ++p) {
#pragma unroll
            for (int s = 0; s < 3; ++s) {
                float c = N1[u][p][0] * Mki[0][s] + N1[u][p][1] * Mki[1][s];
                float d = N1[u][p][2] * Mki[2][s];
                T2p[p][s] = c + d;
                T2m[p][s] = c - d;
            }
        }
#pragma unroll
        for (int v = 0; v < 2; ++v) {
            const float (*T2)[3] = (v == 0) ? T2p : T2m;
            float ss = 0.0f;
#pragma unroll
            for (int p = 0; p < 3; ++p)
#pragma unroll
                for (int s = 0; s < 3; ++s)
                    ss += T2[p][s] * T2[p][s];
            // diag sign on the (2,2) entry is (-1)^(u^v)
            float diag = T2[0][0] + T2[1][1] + (((u ^ v) & 1) ? -T2[2][2] : T2[2][2]);
            float e2 = ss - 2.0f * diag + 3.0f;
            err[u][v] = sqrtf(fmaxf(e2, 0.0f));
        }
    }

    // comb index m = a*4 + b*2 + c  ->  err[a^b][b^c]
    float4 lo, hi;
    {
        float res[8];
#pragma unroll
        for (int m = 0; m < 8; ++m) {
            int a = (m >> 2) & 1, bb = (m >> 1) & 1, c = m & 1;
            res[m] = err[a ^ bb][bb ^ c];
        }
        lo = make_float4(res[0], res[1], res[2], res[3]);
        hi = make_float4(res[4], res[5], res[6], res[7]);
    }
    float4* o = reinterpret_cast<float4*>(out + (size_t)idx * 8);
    o[0] = lo;
    o[1] = hi;
}

extern "C" void kernel_launch(void* const* d_in, const int* in_sizes, int n_in,
                              void* d_out, int out_size, void* d_ws, size_t ws_size,
                              hipStream_t stream)
{
    const float* H    = (const float*)d_in[0];
    const int*   trip = (const int*)d_in[1];
    float*       out  = (float*)d_out;

    const int total = BQ * TT;               // 640,000 threads
    const int block = 256;
    const int grid  = (total + block - 1) / block;  // 2500 blocks
    jcfg_err_kernel<<<grid, block, 0, stream>>>(H, trip, out);
}

// Round 2
// 40.875 us; speedup vs baseline: 1.5075x; 1.5075x over previous
//
#include <hip/hip_runtime.h>

// Problem constants (match reference)
#define BQ 32
#define TT 20000
#define NN 200
#define S3 600              // 3*N
#define JT 25               // j's per repack tile
#define NTILE (NN / JT)     // 8
#define SLOTS (JT * 9)      // 225
#define RELEMS ((size_t)NN * NN * 9 * BQ)   // 11,520,000 floats = 46.08 MB

// ---------------------------------------------------------------------------
// Kernel 1: repack H[b][3i+p][3j+q] -> R[((i*N+j)*9 + p*3+q)*32 + b]
// (batch-innermost 3x3-block layout so the gather is fully coalesced).
// LDS-tiled transpose: coalesced global reads AND coalesced global writes.
// ---------------------------------------------------------------------------
__global__ __launch_bounds__(256) void repack_kernel(
    const float* __restrict__ H, float* __restrict__ R)
{
    __shared__ float lds[SLOTS * 33];   // pad *33: bank = (slot + b) % 32
    const int i   = blockIdx.x / NTILE;
    const int jt  = blockIdx.x % NTILE;
    const int c0  = 3 * JT * jt;        // starting source column
    const int tid = threadIdx.x;
    const int NE  = BQ * 3 * (3 * JT);  // 32 * 3 * 75 = 7200 elements

    // Load phase: coalesced 75-float runs per (b, p)
    for (int e = tid; e < NE; e += 256) {
        int b   = e / 225;
        int rem = e - b * 225;
        int p   = rem / 75;
        int c   = rem - p * 75;
        float val = H[(size_t)b * (S3 * S3) + (size_t)(3 * i + p) * S3 + c0 + c];
        int jl = c / 3, q = c - 3 * jl;
        int slot = jl * 9 + p * 3 + q;
        lds[slot * 33 + b] = val;
    }
    __syncthreads();

    // Store phase: fully coalesced contiguous writes
    float* dst = R + (size_t)(i * NN + JT * jt) * 9 * BQ;
    for (int w = tid; w < SLOTS * BQ; w += 256) {
        int slot = w >> 5, b = w & 31;
        dst[w] = lds[slot * 33 + b];
    }
}

// ---------------------------------------------------------------------------
// Shared compute: four distinct products T2[u][v] = Mij * S^u * Mjk * S^v * Mki
// (S = diag(1,1,-1)); all 8 Frobenius errors derived from them.
// ---------------------------------------------------------------------------
__device__ __forceinline__ void compute_errs(
    const float Mij[9], const float Mjk[9], const float Mki[9], float res[8])
{
    float N1[2][9];
#pragma unroll
    for (int p = 0; p < 3; ++p) {
#pragma unroll
        for (int r = 0; r < 3; ++r) {
            float c = Mij[p*3+0] * Mjk[0*3+r] + Mij[p*3+1] * Mjk[1*3+r];
            float d = Mij[p*3+2] * Mjk[2*3+r];
            N1[0][p*3+r] = c + d;
            N1[1][p*3+r] = c - d;
        }
    }
    float err[2][2];
#pragma unroll
    for (int u = 0; u < 2; ++u) {
        float T2p[9], T2m[9];
#pragma unroll
        for (int p = 0; p < 3; ++p) {
#pragma unroll
            for (int s = 0; s < 3; ++s) {
                float c = N1[u][p*3+0] * Mki[0*3+s] + N1[u][p*3+1] * Mki[1*3+s];
                float d = N1[u][p*3+2] * Mki[2*3+s];
                T2p[p*3+s] = c + d;
                T2m[p*3+s] = c - d;
            }
        }
#pragma unroll
        for (int v = 0; v < 2; ++v) {
            const float* T2 = (v == 0) ? T2p : T2m;
            float ss = 0.0f;
#pragma unroll
            for (int e = 0; e < 9; ++e) ss += T2[e] * T2[e];
            float diag = T2[0] + T2[4] + (((u ^ v) & 1) ? -T2[8] : T2[8]);
            float e2 = ss - 2.0f * diag + 3.0f;
            err[u][v] = sqrtf(fmaxf(e2, 0.0f));
        }
    }
#pragma unroll
    for (int m = 0; m < 8; ++m) {
        int a = (m >> 2) & 1, bb = (m >> 1) & 1, c = m & 1;
        res[m] = err[a ^ bb][bb ^ c];
    }
}

// ---------------------------------------------------------------------------
// Kernel 2: gather from R. lane = g&31 = batch, so 32 lanes sharing one
// triplet read each (block, pq) as one fully-used 128B segment.
// ---------------------------------------------------------------------------
__global__ __launch_bounds__(256) void gather_kernel(
    const float* __restrict__ R, const int* __restrict__ trip,
    float* __restrict__ out)
{
    int g = blockIdx.x * 256 + threadIdx.x;   // grid sized exactly, no bounds check
    int b = g & 31;
    int t = g >> 5;

    int i = trip[3 * t + 0];
    int j = trip[3 * t + 1];
    int k = trip[3 * t + 2];

    const float* __restrict__ Rij = R + (size_t)(i * NN + j) * 288 + b;
    const float* __restrict__ Rjk = R + (size_t)(j * NN + k) * 288 + b;
    const float* __restrict__ Rki = R + (size_t)(k * NN + i) * 288 + b;

    float Mij[9], Mjk[9], Mki[9];
#pragma unroll
    for (int pq = 0; pq < 9; ++pq) {
        Mij[pq] = Rij[pq * 32];
        Mjk[pq] = Rjk[pq * 32];
        Mki[pq] = Rki[pq * 32];
    }

    float res[8];
    compute_errs(Mij, Mjk, Mki, res);

    float* o = out + (size_t)(b * TT + t) * 8;
    *reinterpret_cast<float4*>(o)     = make_float4(res[0], res[1], res[2], res[3]);
    *reinterpret_cast<float4*>(o + 4) = make_float4(res[4], res[5], res[6], res[7]);
}

// ---------------------------------------------------------------------------
// Fallback (round-1 direct kernel) in case ws is too small for R.
// ---------------------------------------------------------------------------
__global__ __launch_bounds__(256) void jcfg_err_direct(
    const float* __restrict__ H,
    const int*   __restrict__ trip,
    float*       __restrict__ out)
{
    int idx = blockIdx.x * blockDim.x + threadIdx.x;
    if (idx >= BQ * TT) return;
    int b = idx / TT;
    int t = idx - b * TT;

    int i = trip[3 * t + 0];
    int j = trip[3 * t + 1];
    int k = trip[3 * t + 2];

    const float* __restrict__ Hb = H + (size_t)b * (S3 * S3);

    float Mij[9], Mjk[9], Mki[9];
    const int ri = 3 * i, rj = 3 * j, rk = 3 * k;
#pragma unroll
    for (int p = 0; p < 3; ++p) {
        const float* rowIJ = Hb + (size_t)(ri + p) * S3 + rj;
        const float* rowJK = Hb + (size_t)(rj + p) * S3 + rk;
        const float* rowKI = Hb + (size_t)(rk + p) * S3 + ri;
#pragma unroll
        for (int q = 0; q < 3; ++q) {
            Mij[p*3+q] = rowIJ[q];
            Mjk[p*3+q] = rowJK[q];
            Mki[p*3+q] = rowKI[q];
        }
    }

    float res[8];
    compute_errs(Mij, Mjk, Mki, res);

    float* o = out + (size_t)idx * 8;
    *reinterpret_cast<float4*>(o)     = make_float4(res[0], res[1], res[2], res[3]);
    *reinterpret_cast<float4*>(o + 4) = make_float4(res[4], res[5], res[6], res[7]);
}

extern "C" void kernel_launch(void* const* d_in, const int* in_sizes, int n_in,
                              void* d_out, int out_size, void* d_ws, size_t ws_size,
                              hipStream_t stream)
{
    const float* H    = (const float*)d_in[0];
    const int*   trip = (const int*)d_in[1];
    float*       out  = (float*)d_out;

    if (ws_size >= RELEMS * sizeof(float)) {
        float* R = (float*)d_ws;
        repack_kernel<<<NN * NTILE, 256, 0, stream>>>(H, R);            // 1600 blocks
        gather_kernel<<<(BQ * TT) / 256, 256, 0, stream>>>(R, trip, out); // 2500 blocks
    } else {
        const int total = BQ * TT;
        jcfg_err_direct<<<(total + 255) / 256, 256, 0, stream>>>(H, trip, out);
    }
}

// Round 4
// 40.146 us; speedup vs baseline: 1.5348x; 1.0181x over previous
//
#include <hip/hip_runtime.h>

// Problem constants (match reference)
#define BQ 32
#define TT 20000
#define NN 200
#define S3 600              // 3*N
#define JT 20               // j's per repack tile (60 floats = 240B runs, 16B-aligned)
#define NTILE (NN / JT)     // 10
#define SLOTS (JT * 9)      // 180
#define RELEMS ((size_t)NN * NN * 9 * BQ)   // 11,520,000 floats = 46.08 MB

typedef float f32x4 __attribute__((ext_vector_type(4)));   // nontemporal-store-compatible

// ---------------------------------------------------------------------------
// Kernel 1: repack H[b][3i+p][3j+q] -> R[((i*N+j)*9 + p*3+q)*32 + b]
// float4 on both the global-load and global-store side.
// ---------------------------------------------------------------------------
__global__ __launch_bounds__(256) void repack_kernel(
    const float* __restrict__ H, float* __restrict__ R)
{
    __shared__ float lds[SLOTS * 33];   // *33 pad: store-phase reads are 2-way (free)
    const int i   = blockIdx.x / NTILE;
    const int jt  = blockIdx.x % NTILE;
    const int c0  = 3 * JT * jt;        // starting source column (floats), 240B-aligned
    const int tid = threadIdx.x;

    // Load phase: 1440 float4 per block, runs of 15 float4 per (b,p)
    const int NE4 = BQ * 3 * 15;        // 1440
    for (int e = tid; e < NE4; e += 256) {
        int b   = e / 45;
        int rem = e - b * 45;
        int p   = rem / 15;
        int c4  = rem - p * 15;
        const float4 v = *reinterpret_cast<const float4*>(
            H + (size_t)b * (S3 * S3) + (size_t)(3 * i + p) * S3 + c0 + 4 * c4);
        const float vv[4] = {v.x, v.y, v.z, v.w};
#pragma unroll
        for (int x = 0; x < 4; ++x) {
            int c  = 4 * c4 + x;
            int jl = c / 3, q = c - 3 * jl;
            lds[(jl * 9 + p * 3 + q) * 33 + b] = vv[x];
        }
    }
    __syncthreads();

    // Store phase: 1440 float4, fully coalesced contiguous writes
    f32x4* dst4 = reinterpret_cast<f32x4*>(R + (size_t)(i * NN + JT * jt) * 9 * BQ);
    const int NW4 = SLOTS * BQ / 4;     // 1440
    for (int w = tid; w < NW4; w += 256) {
        int slot = w >> 3;
        int bq   = (w & 7) * 4;
        f32x4 v;
        v.x = lds[slot * 33 + bq + 0];
        v.y = lds[slot * 33 + bq + 1];
        v.z = lds[slot * 33 + bq + 2];
        v.w = lds[slot * 33 + bq + 3];
        dst4[w] = v;
    }
}

// ---------------------------------------------------------------------------
// Shared compute: four distinct products T2[u][v] = Mij * S^u * Mjk * S^v * Mki
// (S = diag(1,1,-1)); all 8 Frobenius errors derived from them.
// ---------------------------------------------------------------------------
__device__ __forceinline__ void compute_errs(
    const float Mij[9], const float Mjk[9], const float Mki[9], float res[8])
{
    float N1[2][9];
#pragma unroll
    for (int p = 0; p < 3; ++p) {
#pragma unroll
        for (int r = 0; r < 3; ++r) {
            float c = Mij[p*3+0] * Mjk[0*3+r] + Mij[p*3+1] * Mjk[1*3+r];
            float d = Mij[p*3+2] * Mjk[2*3+r];
            N1[0][p*3+r] = c + d;
            N1[1][p*3+r] = c - d;
        }
    }
    float err[2][2];
#pragma unroll
    for (int u = 0; u < 2; ++u) {
        float T2p[9], T2m[9];
#pragma unroll
        for (int p = 0; p < 3; ++p) {
#pragma unroll
            for (int s = 0; s < 3; ++s) {
                float c = N1[u][p*3+0] * Mki[0*3+s] + N1[u][p*3+1] * Mki[1*3+s];
                float d = N1[u][p*3+2] * Mki[2*3+s];
                T2p[p*3+s] = c + d;
                T2m[p*3+s] = c - d;
            }
        }
#pragma unroll
        for (int v = 0; v < 2; ++v) {
            const float* T2 = (v == 0) ? T2p : T2m;
            float ss = 0.0f;
#pragma unroll
            for (int e = 0; e < 9; ++e) ss += T2[e] * T2[e];
            float diag = T2[0] + T2[4] + (((u ^ v) & 1) ? -T2[8] : T2[8]);
            float e2 = ss - 2.0f * diag + 3.0f;
            err[u][v] = sqrtf(fmaxf(e2, 0.0f));
        }
    }
#pragma unroll
    for (int m = 0; m < 8; ++m) {
        int a = (m >> 2) & 1, bb = (m >> 1) & 1, c = m & 1;
        res[m] = err[a ^ bb][bb ^ c];
    }
}

// ---------------------------------------------------------------------------
// Kernel 2: gather from R. lane = g&31 = batch, so 32 lanes sharing one
// triplet read each (block, pq) as one fully-used 128B segment.
// ---------------------------------------------------------------------------
__global__ __launch_bounds__(256) void gather_kernel(
    const float* __restrict__ R, const int* __restrict__ trip,
    float* __restrict__ out)
{
    int g = blockIdx.x * 256 + threadIdx.x;   // grid sized exactly, no bounds check
    int b = g & 31;
    int t = g >> 5;

    int i = trip[3 * t + 0];
    int j = trip[3 * t + 1];
    int k = trip[3 * t + 2];

    const float* __restrict__ Rij = R + (size_t)(i * NN + j) * 288 + b;
    const float* __restrict__ Rjk = R + (size_t)(j * NN + k) * 288 + b;
    const float* __restrict__ Rki = R + (size_t)(k * NN + i) * 288 + b;

    float Mij[9], Mjk[9], Mki[9];
#pragma unroll
    for (int pq = 0; pq < 9; ++pq) {
        Mij[pq] = Rij[pq * 32];
        Mjk[pq] = Rjk[pq * 32];
        Mki[pq] = Rki[pq * 32];
    }

    float res[8];
    compute_errs(Mij, Mjk, Mki, res);

    // out is never re-read by us: nontemporal streaming stores
    f32x4* o4 = reinterpret_cast<f32x4*>(out + (size_t)(b * TT + t) * 8);
    f32x4 lo, hi;
    lo.x = res[0]; lo.y = res[1]; lo.z = res[2]; lo.w = res[3];
    hi.x = res[4]; hi.y = res[5]; hi.z = res[6]; hi.w = res[7];
    __builtin_nontemporal_store(lo, o4);
    __builtin_nontemporal_store(hi, o4 + 1);
}

// ---------------------------------------------------------------------------
// Fallback (round-1 direct kernel) in case ws is too small for R.
// ---------------------------------------------------------------------------
__global__ __launch_bounds__(256) void jcfg_err_direct(
    const float* __restrict__ H,
    const int*   __restrict__ trip,
    float*       __restrict__ out)
{
    int idx = blockIdx.x * blockDim.x + threadIdx.x;
    if (idx >= BQ * TT) return;
    int b = idx / TT;
    int t = idx - b * TT;

    int i = trip[3 * t + 0];
    int j = trip[3 * t + 1];
    int k = trip[3 * t + 2];

    const float* __restrict__ Hb = H + (size_t)b * (S3 * S3);

    float Mij[9], Mjk[9], Mki[9];
    const int ri = 3 * i, rj = 3 * j, rk = 3 * k;
#pragma unroll
    for (int p = 0; p < 3; ++p) {
        const float* rowIJ = Hb + (size_t)(ri + p) * S3 + rj;
        const float* rowJK = Hb + (size_t)(rj + p) * S3 + rk;
        const float* rowKI = Hb + (size_t)(rk + p) * S3 + ri;
#pragma unroll
        for (int q = 0; q < 3; ++q) {
            Mij[p*3+q] = rowIJ[q];
            Mjk[p*3+q] = rowJK[q];
            Mki[p*3+q] = rowKI[q];
        }
    }

    float res[8];
    compute_errs(Mij, Mjk, Mki, res);

    float* o = out + (size_t)idx * 8;
    *reinterpret_cast<float4*>(o)     = make_float4(res[0], res[1], res[2], res[3]);
    *reinterpret_cast<float4*>(o + 4) = make_float4(res[4], res[5], res[6], res[7]);
}

extern "C" void kernel_launch(void* const* d_in, const int* in_sizes, int n_in,
                              void* d_out, int out_size, void* d_ws, size_t ws_size,
                              hipStream_t stream)
{
    const float* H    = (const float*)d_in[0];
    const int*   trip = (const int*)d_in[1];
    float*       out  = (float*)d_out;

    if (ws_size >= RELEMS * sizeof(float)) {
        float* R = (float*)d_ws;
        repack_kernel<<<NN * NTILE, 256, 0, stream>>>(H, R);              // 2000 blocks
        gather_kernel<<<(BQ * TT) / 256, 256, 0, stream>>>(R, trip, out); // 2500 blocks
    } else {
        const int total = BQ * TT;
        jcfg_err_direct<<<(total + 255) / 256, 256, 0, stream>>>(H, trip, out);
    }
}

// Round 5
// 39.421 us; speedup vs baseline: 1.5631x; 1.0184x over previous
//
#include <hip/hip_runtime.h>

// Problem constants (match reference)
#define BQ 32
#define TT 20000
#define NN 200
#define S3 600              // 3*N
#define JT 20               // j's per repack tile (60 floats = 240B runs, 16B-aligned)
#define NTILE (NN / JT)     // 10
#define SLOTS (JT * 9)      // 180
#define RELEMS ((size_t)NN * NN * 9 * BQ)   // 11,520,000 floats = 46.08 MB

typedef float f32x4 __attribute__((ext_vector_type(4)));   // nontemporal-store-compatible

// ---------------------------------------------------------------------------
// Kernel 1: repack H[b][3i+p][3j+q] -> R[((i*N+j)*9 + p*3+q)*32 + b]
// float4 on both the global-load and global-store side.
// ---------------------------------------------------------------------------
__global__ __launch_bounds__(256) void repack_kernel(
    const float* __restrict__ H, float* __restrict__ R)
{
    __shared__ float lds[SLOTS * 33];   // *33 pad: store-phase reads are 2-way (free)
    const int i   = blockIdx.x / NTILE;
    const int jt  = blockIdx.x % NTILE;
    const int c0  = 3 * JT * jt;        // starting source column (floats), 240B-aligned
    const int tid = threadIdx.x;

    // Load phase: 1440 float4 per block, runs of 15 float4 per (b,p)
    const int NE4 = BQ * 3 * 15;        // 1440
    for (int e = tid; e < NE4; e += 256) {
        int b   = e / 45;
        int rem = e - b * 45;
        int p   = rem / 15;
        int c4  = rem - p * 15;
        const float4 v = *reinterpret_cast<const float4*>(
            H + (size_t)b * (S3 * S3) + (size_t)(3 * i + p) * S3 + c0 + 4 * c4);
        const float vv[4] = {v.x, v.y, v.z, v.w};
#pragma unroll
        for (int x = 0; x < 4; ++x) {
            int c  = 4 * c4 + x;
            int jl = c / 3, q = c - 3 * jl;
            lds[(jl * 9 + p * 3 + q) * 33 + b] = vv[x];
        }
    }
    __syncthreads();

    // Store phase: 1440 float4, fully coalesced contiguous writes
    f32x4* dst4 = reinterpret_cast<f32x4*>(R + (size_t)(i * NN + JT * jt) * 9 * BQ);
    const int NW4 = SLOTS * BQ / 4;     // 1440
    for (int w = tid; w < NW4; w += 256) {
        int slot = w >> 3;
        int bq   = (w & 7) * 4;
        f32x4 v;
        v.x = lds[slot * 33 + bq + 0];
        v.y = lds[slot * 33 + bq + 1];
        v.z = lds[slot * 33 + bq + 2];
        v.w = lds[slot * 33 + bq + 3];
        dst4[w] = v;
    }
}

// ---------------------------------------------------------------------------
// Shared compute: four distinct products T2[u][v] = Mij * S^u * Mjk * S^v * Mki
// (S = diag(1,1,-1)); all 8 Frobenius errors derived from them.
// ---------------------------------------------------------------------------
__device__ __forceinline__ void compute_errs(
    const float Mij[9], const float Mjk[9], const float Mki[9], float res[8])
{
    float N1[2][9];
#pragma unroll
    for (int p = 0; p < 3; ++p) {
#pragma unroll
        for (int r = 0; r < 3; ++r) {
            float c = Mij[p*3+0] * Mjk[0*3+r] + Mij[p*3+1] * Mjk[1*3+r];
            float d = Mij[p*3+2] * Mjk[2*3+r];
            N1[0][p*3+r] = c + d;
            N1[1][p*3+r] = c - d;
        }
    }
    float err[2][2];
#pragma unroll
    for (int u = 0; u < 2; ++u) {
        float T2p[9], T2m[9];
#pragma unroll
        for (int p = 0; p < 3; ++p) {
#pragma unroll
            for (int s = 0; s < 3; ++s) {
                float c = N1[u][p*3+0] * Mki[0*3+s] + N1[u][p*3+1] * Mki[1*3+s];
                float d = N1[u][p*3+2] * Mki[2*3+s];
                T2p[p*3+s] = c + d;
                T2m[p*3+s] = c - d;
            }
        }
#pragma unroll
        for (int v = 0; v < 2; ++v) {
            const float* T2 = (v == 0) ? T2p : T2m;
            float ss = 0.0f;
#pragma unroll
            for (int e = 0; e < 9; ++e) ss += T2[e] * T2[e];
            float diag = T2[0] + T2[4] + (((u ^ v) & 1) ? -T2[8] : T2[8]);
            float e2 = ss - 2.0f * diag + 3.0f;
            err[u][v] = sqrtf(fmaxf(e2, 0.0f));
        }
    }
#pragma unroll
    for (int m = 0; m < 8; ++m) {
        int a = (m >> 2) & 1, bb = (m >> 1) & 1, c = m & 1;
        res[m] = err[a ^ bb][bb ^ c];
    }
}

// ---------------------------------------------------------------------------
// Kernel 2: gather from R, 4 batches per thread via f32x4 loads.
// Thread (t, bg) handles batches 4*bg .. 4*bg+3 of triplet t.
// Per pq, the 8 bg-lanes of one t cover a full contiguous 128B segment.
// 27 x 16B loads in flight per thread (432B) -> latency-tolerant.
// ---------------------------------------------------------------------------
__global__ __launch_bounds__(256, 2) void gather4_kernel(
    const float* __restrict__ R, const int* __restrict__ trip,
    float* __restrict__ out)
{
    int g  = blockIdx.x * 256 + threadIdx.x;   // 160000 threads exactly
    int bg = g & 7;
    int t  = g >> 3;

    int i = trip[3 * t + 0];
    int j = trip[3 * t + 1];
    int k = trip[3 * t + 2];

    // f32x4 index: pair*72 + pq*8 + bg
    const f32x4* __restrict__ Rij = reinterpret_cast<const f32x4*>(R) + (size_t)(i * NN + j) * 72 + bg;
    const f32x4* __restrict__ Rjk = reinterpret_cast<const f32x4*>(R) + (size_t)(j * NN + k) * 72 + bg;
    const f32x4* __restrict__ Rki = reinterpret_cast<const f32x4*>(R) + (size_t)(k * NN + i) * 72 + bg;

    f32x4 Aij[9], Ajk[9], Aki[9];
#pragma unroll
    for (int pq = 0; pq < 9; ++pq) {
        Aij[pq] = Rij[pq * 8];
        Ajk[pq] = Rjk[pq * 8];
        Aki[pq] = Rki[pq * 8];
    }

#pragma unroll
    for (int u = 0; u < 4; ++u) {        // u is compile-time after unroll
        float Mij[9], Mjk[9], Mki[9];
#pragma unroll
        for (int pq = 0; pq < 9; ++pq) {
            Mij[pq] = Aij[pq][u];
            Mjk[pq] = Ajk[pq][u];
            Mki[pq] = Aki[pq][u];
        }
        float res[8];
        compute_errs(Mij, Mjk, Mki, res);

        int b = 4 * bg + u;
        f32x4* o4 = reinterpret_cast<f32x4*>(out + ((size_t)b * TT + t) * 8);
        f32x4 lo, hi;
        lo.x = res[0]; lo.y = res[1]; lo.z = res[2]; lo.w = res[3];
        hi.x = res[4]; hi.y = res[5]; hi.z = res[6]; hi.w = res[7];
        __builtin_nontemporal_store(lo, o4);
        __builtin_nontemporal_store(hi, o4 + 1);
    }
}

// ---------------------------------------------------------------------------
// Fallback (round-1 direct kernel) in case ws is too small for R.
// ---------------------------------------------------------------------------
__global__ __launch_bounds__(256) void jcfg_err_direct(
    const float* __restrict__ H,
    const int*   __restrict__ trip,
    float*       __restrict__ out)
{
    int idx = blockIdx.x * blockDim.x + threadIdx.x;
    if (idx >= BQ * TT) return;
    int b = idx / TT;
    int t = idx - b * TT;

    int i = trip[3 * t + 0];
    int j = trip[3 * t + 1];
    int k = trip[3 * t + 2];

    const float* __restrict__ Hb = H + (size_t)b * (S3 * S3);

    float Mij[9], Mjk[9], Mki[9];
    const int ri = 3 * i, rj = 3 * j, rk = 3 * k;
#pragma unroll
    for (int p = 0; p < 3; ++p) {
        const float* rowIJ = Hb + (size_t)(ri + p) * S3 + rj;
        const float* rowJK = Hb + (size_t)(rj + p) * S3 + rk;
        const float* rowKI = Hb + (size_t)(rk + p) * S3 + ri;
#pragma unroll
        for (int q = 0; q < 3; ++q) {
            Mij[p*3+q] = rowIJ[q];
            Mjk[p*3+q] = rowJK[q];
            Mki[p*3+q] = rowKI[q];
        }
    }

    float res[8];
    compute_errs(Mij, Mjk, Mki, res);

    float* o = out + (size_t)idx * 8;
    *reinterpret_cast<float4*>(o)     = make_float4(res[0], res[1], res[2], res[3]);
    *reinterpret_cast<float4*>(o + 4) = make_float4(res[4], res[5], res[6], res[7]);
}

extern "C" void kernel_launch(void* const* d_in, const int* in_sizes, int n_in,
                              void* d_out, int out_size, void* d_ws, size_t ws_size,
                              hipStream_t stream)
{
    const float* H    = (const float*)d_in[0];
    const int*   trip = (const int*)d_in[1];
    float*       out  = (float*)d_out;

    if (ws_size >= RELEMS * sizeof(float)) {
        float* R = (float*)d_ws;
        repack_kernel<<<NN * NTILE, 256, 0, stream>>>(H, R);               // 2000 blocks
        gather4_kernel<<<(TT * 8) / 256, 256, 0, stream>>>(R, trip, out);  // 625 blocks
    } else {
        const int total = BQ * TT;
        jcfg_err_direct<<<(total + 255) / 256, 256, 0, stream>>>(H, trip, out);
    }
}

// Round 6
// 32.550 us; speedup vs baseline: 1.8931x; 1.2111x over previous
//
#include <hip/hip_runtime.h>

// Problem constants (match reference)
#define BQ 32
#define TT 20000
#define NN 200
#define S3 600              // 3*N
#define JT 20               // j's per repack tile (60 floats = 240B runs, 16B-aligned)
#define NTILE (NN / JT)     // 10
#define SLOTS (JT * 9)      // 180
#define RELEMS ((size_t)NN * NN * 9 * BQ)   // 11,520,000 elements; fp16 -> 23.04 MB

typedef float    f32x4 __attribute__((ext_vector_type(4)));
typedef _Float16 f16x8 __attribute__((ext_vector_type(8)));   // 16B
typedef _Float16 f16x4 __attribute__((ext_vector_type(4)));   // 8B

// ---------------------------------------------------------------------------
// Kernel 1: repack H[b][3i+p][3j+q] -> R_f16[((i*N+j)*9 + p*3+q)*32 + b]
// fp32 float4 loads -> fp32 LDS (x33 pad, conflict-free) -> fp16 16B stores.
// ---------------------------------------------------------------------------
__global__ __launch_bounds__(256) void repack_kernel(
    const float* __restrict__ H, _Float16* __restrict__ R)
{
    __shared__ float lds[SLOTS * 33];
    const int i   = blockIdx.x / NTILE;
    const int jt  = blockIdx.x % NTILE;
    const int c0  = 3 * JT * jt;        // starting source column (floats)
    const int tid = threadIdx.x;

    // Load phase: 1440 float4 per block, runs of 15 float4 per (b,p)
    const int NE4 = BQ * 3 * 15;        // 1440
    for (int e = tid; e < NE4; e += 256) {
        int b   = e / 45;
        int rem = e - b * 45;
        int p   = rem / 15;
        int c4  = rem - p * 15;
        const float4 v = *reinterpret_cast<const float4*>(
            H + (size_t)b * (S3 * S3) + (size_t)(3 * i + p) * S3 + c0 + 4 * c4);
        const float vv[4] = {v.x, v.y, v.z, v.w};
#pragma unroll
        for (int x = 0; x < 4; ++x) {
            int c  = 4 * c4 + x;
            int jl = c / 3, q = c - 3 * jl;
            lds[(jl * 9 + p * 3 + q) * 33 + b] = vv[x];
        }
    }
    __syncthreads();

    // Store phase: 720 x 16B fp16 stores, fully coalesced contiguous.
    // LDS read banks: (slot + 8*(w&3) + x) mod 32 -> max 2-way (free).
    f16x8* dst8 = reinterpret_cast<f16x8*>(R + (size_t)(i * NN + JT * jt) * 9 * BQ);
    const int NW8 = SLOTS * BQ / 8;     // 720
    for (int w = tid; w < NW8; w += 256) {
        int slot = w >> 2;
        int bh   = (w & 3) * 8;
        f16x8 v;
#pragma unroll
        for (int x = 0; x < 8; ++x)
            v[x] = (_Float16)lds[slot * 33 + bh + x];
        dst8[w] = v;
    }
}

// ---------------------------------------------------------------------------
// Shared compute: four distinct products T2[u][v] = Mij * S^u * Mjk * S^v * Mki
// (S = diag(1,1,-1)); all 8 Frobenius errors derived from them.
// ---------------------------------------------------------------------------
__device__ __forceinline__ void compute_errs(
    const float Mij[9], const float Mjk[9], const float Mki[9], float res[8])
{
    float N1[2][9];
#pragma unroll
    for (int p = 0; p < 3; ++p) {
#pragma unroll
        for (int r = 0; r < 3; ++r) {
            float c = Mij[p*3+0] * Mjk[0*3+r] + Mij[p*3+1] * Mjk[1*3+r];
            float d = Mij[p*3+2] * Mjk[2*3+r];
            N1[0][p*3+r] = c + d;
            N1[1][p*3+r] = c - d;
        }
    }
    float err[2][2];
#pragma unroll
    for (int u = 0; u < 2; ++u) {
        float T2p[9], T2m[9];
#pragma unroll
        for (int p = 0; p < 3; ++p) {
#pragma unroll
            for (int s = 0; s < 3; ++s) {
                float c = N1[u][p*3+0] * Mki[0*3+s] + N1[u][p*3+1] * Mki[1*3+s];
                float d = N1[u][p*3+2] * Mki[2*3+s];
                T2p[p*3+s] = c + d;
                T2m[p*3+s] = c - d;
            }
        }
#pragma unroll
        for (int v = 0; v < 2; ++v) {
            const float* T2 = (v == 0) ? T2p : T2m;
            float ss = 0.0f;
#pragma unroll
            for (int e = 0; e < 9; ++e) ss += T2[e] * T2[e];
            float diag = T2[0] + T2[4] + (((u ^ v) & 1) ? -T2[8] : T2[8]);
            float e2 = ss - 2.0f * diag + 3.0f;
            err[u][v] = sqrtf(fmaxf(e2, 0.0f));
        }
    }
#pragma unroll
    for (int m = 0; m < 8; ++m) {
        int a = (m >> 2) & 1, bb = (m >> 1) & 1, c = m & 1;
        res[m] = err[a ^ bb][bb ^ c];
    }
}

// ---------------------------------------------------------------------------
// Kernel 2: gather from fp16 R, 4 batches per thread via 8B f16x4 loads.
// Thread (t, bg): batches 4*bg..4*bg+3. 8 bg-lanes cover one 64B segment/pq.
// 27 x 8B loads in flight per thread; compute in fp32.
// ---------------------------------------------------------------------------
__global__ __launch_bounds__(256, 2) void gather4_kernel(
    const _Float16* __restrict__ R, const int* __restrict__ trip,
    float* __restrict__ out)
{
    int g  = blockIdx.x * 256 + threadIdx.x;   // 160000 threads exactly
    int bg = g & 7;
    int t  = g >> 3;

    int i = trip[3 * t + 0];
    int j = trip[3 * t + 1];
    int k = trip[3 * t + 2];

    // f16x4 index: pair*72 + pq*8 + bg   (288 halfs per pair = 72 f16x4)
    const f16x4* __restrict__ Rij = reinterpret_cast<const f16x4*>(R) + (size_t)(i * NN + j) * 72 + bg;
    const f16x4* __restrict__ Rjk = reinterpret_cast<const f16x4*>(R) + (size_t)(j * NN + k) * 72 + bg;
    const f16x4* __restrict__ Rki = reinterpret_cast<const f16x4*>(R) + (size_t)(k * NN + i) * 72 + bg;

    f16x4 Aij[9], Ajk[9], Aki[9];
#pragma unroll
    for (int pq = 0; pq < 9; ++pq) {
        Aij[pq] = Rij[pq * 8];
        Ajk[pq] = Rjk[pq * 8];
        Aki[pq] = Rki[pq * 8];
    }

#pragma unroll
    for (int u = 0; u < 4; ++u) {        // compile-time u after unroll
        float Mij[9], Mjk[9], Mki[9];
#pragma unroll
        for (int pq = 0; pq < 9; ++pq) {
            Mij[pq] = (float)Aij[pq][u];
            Mjk[pq] = (float)Ajk[pq][u];
            Mki[pq] = (float)Aki[pq][u];
        }
        float res[8];
        compute_errs(Mij, Mjk, Mki, res);

        int b = 4 * bg + u;
        f32x4* o4 = reinterpret_cast<f32x4*>(out + ((size_t)b * TT + t) * 8);
        f32x4 lo, hi;
        lo.x = res[0]; lo.y = res[1]; lo.z = res[2]; lo.w = res[3];
        hi.x = res[4]; hi.y = res[5]; hi.z = res[6]; hi.w = res[7];
        __builtin_nontemporal_store(lo, o4);
        __builtin_nontemporal_store(hi, o4 + 1);
    }
}

// ---------------------------------------------------------------------------
// Fallback (round-1 direct kernel) in case ws is too small for R.
// ---------------------------------------------------------------------------
__global__ __launch_bounds__(256) void jcfg_err_direct(
    const float* __restrict__ H,
    const int*   __restrict__ trip,
    float*       __restrict__ out)
{
    int idx = blockIdx.x * blockDim.x + threadIdx.x;
    if (idx >= BQ * TT) return;
    int b = idx / TT;
    int t = idx - b * TT;

    int i = trip[3 * t + 0];
    int j = trip[3 * t + 1];
    int k = trip[3 * t + 2];

    const float* __restrict__ Hb = H + (size_t)b * (S3 * S3);

    float Mij[9], Mjk[9], Mki[9];
    const int ri = 3 * i, rj = 3 * j, rk = 3 * k;
#pragma unroll
    for (int p = 0; p < 3; ++p) {
        const float* rowIJ = Hb + (size_t)(ri + p) * S3 + rj;
        const float* rowJK = Hb + (size_t)(rj + p) * S3 + rk;
        const float* rowKI = Hb + (size_t)(rk + p) * S3 + ri;
#pragma unroll
        for (int q = 0; q < 3; ++q) {
            Mij[p*3+q] = rowIJ[q];
            Mjk[p*3+q] = rowJK[q];
            Mki[p*3+q] = rowKI[q];
        }
    }

    float res[8];
    compute_errs(Mij, Mjk, Mki, res);

    float* o = out + (size_t)idx * 8;
    *reinterpret_cast<float4*>(o)     = make_float4(res[0], res[1], res[2], res[3]);
    *reinterpret_cast<float4*>(o + 4) = make_float4(res[4], res[5], res[6], res[7]);
}

extern "C" void kernel_launch(void* const* d_in, const int* in_sizes, int n_in,
                              void* d_out, int out_size, void* d_ws, size_t ws_size,
                              hipStream_t stream)
{
    const float* H    = (const float*)d_in[0];
    const int*   trip = (const int*)d_in[1];
    float*       out  = (float*)d_out;

    if (ws_size >= RELEMS * sizeof(_Float16)) {
        _Float16* R = (_Float16*)d_ws;
        repack_kernel<<<NN * NTILE, 256, 0, stream>>>(H, R);               // 2000 blocks
        gather4_kernel<<<(TT * 8) / 256, 256, 0, stream>>>(R, trip, out);  // 625 blocks
    } else {
        const int total = BQ * TT;
        jcfg_err_direct<<<(total + 255) / 256, 256, 0, stream>>>(H, trip, out);
    }
}